// Round 10
// baseline (119.098 us; speedup 1.0000x reference)
//
#include <hip/hip_runtime.h>
#include <hip/hip_fp16.h>

#define BB 4096
#define CC 512
#define TT 4096
#define NN 1023
#define NL 1024
#define DEPTH 10

// ===================== pre-kernels (write d_ws) =====================

__device__ __forceinline__ unsigned pack_node(float th, int o) {
    return ((unsigned)o << 16) | (unsigned)__half_as_ushort(__float2half(th));
}

// pk_lo[t][j] j=0..511: slot j -> node j-1 (depths 0..8); slot 0 = 0.
// tails[t][i] i=0..255 (depth-8 slot 256+i):
//   {ndL (slot 512+2i), ndR (slot 513+2i), w01, w23}  (leaves 4i..4i+3, f16)
__global__ __launch_bounds__(256)
void pack_trees(const float* __restrict__ thr, const int* __restrict__ ord,
                const float* __restrict__ wts,
                unsigned* __restrict__ pk_lo, uint4* __restrict__ tails) {
    int t = blockIdx.x, tid = threadIdx.x;
    const float* tr = thr + (size_t)t * NN;
    const int*   oo = ord + (size_t)t * NN;
    unsigned* plo = pk_lo + ((size_t)t << 9);
    #pragma unroll
    for (int k = 0; k < 2; ++k) {
        int j = k * 256 + tid;
        plo[j] = (j == 0) ? 0u : pack_node(tr[j - 1], oo[j - 1]);
    }
    int i = tid;
    int nL = 511 + 2 * i, nR = 512 + 2 * i;
    unsigned ndL = pack_node(tr[nL], oo[nL]);
    unsigned ndR = pack_node(tr[nR], oo[nR]);
    float4 w4 = *(const float4*)(wts + ((size_t)t << 10) + 4 * i);
    unsigned w01 = (unsigned)__half_as_ushort(__float2half(w4.x)) |
                   ((unsigned)__half_as_ushort(__float2half(w4.y)) << 16);
    unsigned w23 = (unsigned)__half_as_ushort(__float2half(w4.z)) |
                   ((unsigned)__half_as_ushort(__float2half(w4.w)) << 16);
    tails[((size_t)t << 8) + i] = make_uint4(ndL, ndR, w01, w23);
}

// xt16[c*4096 + b] = f16bits(x[b][c])  — f32 transpose via padded LDS tile
__global__ __launch_bounds__(256)
void pack_x16(const float* __restrict__ x, unsigned short* __restrict__ xt16) {
    __shared__ float tile[64][65];
    int tx = threadIdx.x & 63, ty = threadIdx.x >> 6;   // 64 x 4
    int b0 = blockIdx.x * 64;
    int c0 = blockIdx.y * 64;
    #pragma unroll
    for (int i = 0; i < 16; ++i) {
        int rr = i * 4 + ty;
        tile[rr][tx] = x[(size_t)(b0 + rr) * CC + c0 + tx];
    }
    __syncthreads();
    #pragma unroll
    for (int i = 0; i < 16; ++i) {
        int cr = i * 4 + ty;
        xt16[(size_t)(c0 + cr) * BB + b0 + tx] =
            __half_as_ushort(__float2half(tile[tx][cr]));
    }
}

// ===================== packed helpers (VOP3P-lowering, portable) =====================
typedef unsigned short u16x2 __attribute__((ext_vector_type(2)));

static __device__ __forceinline__ unsigned psub_f16x2(unsigned a, unsigned b) {
    __half2 ah, bh;
    __builtin_memcpy(&ah, &a, 4);
    __builtin_memcpy(&bh, &b, 4);
    __half2 r = ah - bh;                       // v_pk_add_f16 (neg)
    unsigned u; __builtin_memcpy(&u, &r, 4); return u;
}
static __device__ __forceinline__ unsigned pmin_u16x2(unsigned a, unsigned b) {
    u16x2 av, bv;
    __builtin_memcpy(&av, &a, 4);
    __builtin_memcpy(&bv, &b, 4);
    u16x2 m = __builtin_elementwise_min(av, bv);  // v_pk_min_u16
    unsigned u; __builtin_memcpy(&u, &m, 4); return u;
}
static __device__ __forceinline__ float f16lo_to_f32(unsigned u) {
    return __half2float(__ushort_as_half((unsigned short)(u & 0xffffu)));
}
static __device__ __forceinline__ float f16hi_to_f32(unsigned u) {
    return __half2float(__ushort_as_half((unsigned short)(u >> 16)));
}

// ===================== main kernel =====================
// grid 2048, XCD-swizzled. 1024 threads = 16 waves (4/SIMD), lane = sample,
// 2 chains/thread (packed f16 eval), 4 groups x 32 trees. Depths 0..8 staged
// (512 slots, 2KB/tree) per-wave. Level 9 + weights via speculative 32B tail pair.
// LDS (160 KiB): xs16 u16[512][64] 64K @0 | trees 64K @64K | res f32[64][128] 32K @128K
#define LDS_BYTES 163840

typedef __attribute__((address_space(1))) const void gv_t;
typedef __attribute__((address_space(3))) void lv_t;

__global__ __launch_bounds__(1024, 1)
void rhf_main(const unsigned* __restrict__ pk_lo, const uint4* __restrict__ tails,
              const unsigned short* __restrict__ xt16, float* __restrict__ out) {
    extern __shared__ char smem[];
    unsigned short* xs16 = (unsigned short*)smem;
    unsigned*       trl  = (unsigned*)(smem + 65536);
    float*          res  = (float*)(smem + 131072);

    const int tid  = threadIdx.x;
    const int lane = tid & 63;
    const int wv   = tid >> 6;          // 0..15
    const int bi   = blockIdx.x;
    const int tb    = ((bi & 7) << 2) + ((bi >> 3) >> 6);   // 0..31
    const int panel = (bi >> 3) & 63;                       // 0..63

    // ---- per-wave tree DMA: 2 trees x 2KB = 4KB = 4 x (64 lanes x 16B) ----
    const char* gsrc0 = (const char*)pk_lo + ((size_t)(tb * 128) << 11);
    char* ldst = (char*)trl + wv * 4096 + lane * 16;
    auto dma = [&](int g) {
        const char* s = gsrc0 + ((size_t)(g * 32 + wv * 2) << 11) + lane * 16;
        #pragma unroll
        for (int q = 0; q < 4; ++q)
            __builtin_amdgcn_global_load_lds((gv_t*)(s + q * 1024),
                                             (lv_t*)(ldst + q * 1024), 16, 0, 0);
    };

    dma(0);

    // ---- stage xs16 (coalesced 16B, linear LDS writes) ----
    {
        const unsigned short* src = xt16 + (size_t)panel * 64;
        #pragma unroll
        for (int k = 0; k < 4; ++k) {
            int i4 = k * 1024 + tid;
            int c  = i4 >> 3;
            int o8 = (i4 & 7) << 3;
            uint4 v = *(const uint4*)(src + (size_t)c * BB + o8);
            *(uint4*)(xs16 + ((size_t)i4 << 3)) = v;
        }
    }
    __syncthreads();   // xs16 visible; DMA(0) drained

    #pragma unroll 1
    for (int g = 0; g < 4; ++g) {
        if (g > 0) {
            asm volatile("s_waitcnt vmcnt(0)" ::: "memory");
            __builtin_amdgcn_sched_barrier(0);
        }
        const int t0 = tb * 128 + g * 32 + wv * 2;
        const unsigned* pkw = trl + wv * 1024;

        unsigned amin2u = 0x7c007c00u;          // {+inf, +inf} f16
        int sl0 = 1, sl1 = 1;
        unsigned nd0 = pkw[1], nd1 = pkw[512 + 1];
        uint4 recL0, recR0, recL1, recR1;

        #pragma unroll
        for (int d = 0; d < 9; ++d) {
            uint2 ch0, ch1;
            if (d < 8) {
                ch0 = *(const uint2*)(pkw + 2 * sl0);          // LDS b64
                ch1 = *(const uint2*)(pkw + 512 + 2 * sl1);
            }
            if (d == 7) {   // speculative 32B tail pair (sibling records)
                const uint4* tp0 = tails + ((size_t)t0 << 8) + 2 * (sl0 - 128);
                const uint4* tp1 = tails + ((size_t)(t0 + 1) << 8) + 2 * (sl1 - 128);
                recL0 = tp0[0]; recR0 = tp0[1];
                recL1 = tp1[0]; recR1 = tp1[1];
            }
            unsigned thv2  = (nd0 & 0xffffu) | (nd1 << 16);
            unsigned short f0 = xs16[((nd0 >> 16) << 6) + lane];
            unsigned short f1 = xs16[((nd1 >> 16) << 6) + lane];
            unsigned feat2 = (unsigned)f0 | ((unsigned)f1 << 16);
            unsigned mb = psub_f16x2(feat2, thv2);
            amin2u = pmin_u16x2(amin2u, mb & 0x7fff7fffu);
            unsigned r0 = ((mb >> 15) & 1u) ^ 1u;
            unsigned r1 = (mb >> 31) ^ 1u;
            sl0 = 2 * sl0 + (int)r0;
            sl1 = 2 * sl1 + (int)r1;
            if (d < 8) {
                nd0 = r0 ? ch0.y : ch0.x;
                nd1 = r1 ? ch1.y : ch1.x;
            }
        }

        if (g < 3) { dma(g + 1); __builtin_amdgcn_sched_barrier(0); }

        // ---- tail: level 9 + fused weight (packed) ----
        // sl now = depth-9 slot: r7 = (sl>>1)&1, r8 = sl&1
        int r7_0 = (sl0 >> 1) & 1, r8_0 = sl0 & 1;
        int r7_1 = (sl1 >> 1) & 1, r8_1 = sl1 & 1;
        unsigned ndA0 = r8_0 ? recL0.y : recL0.x;
        unsigned ndB0 = r8_0 ? recR0.y : recR0.x;
        unsigned nd9_0 = r7_0 ? ndB0 : ndA0;
        unsigned ndA1 = r8_1 ? recL1.y : recL1.x;
        unsigned ndB1 = r8_1 ? recR1.y : recR1.x;
        unsigned nd9_1 = r7_1 ? ndB1 : ndA1;

        unsigned thv2  = (nd9_0 & 0xffffu) | (nd9_1 << 16);
        unsigned short f0 = xs16[((nd9_0 >> 16) << 6) + lane];
        unsigned short f1 = xs16[((nd9_1 >> 16) << 6) + lane];
        unsigned feat2 = (unsigned)f0 | ((unsigned)f1 << 16);
        unsigned mb = psub_f16x2(feat2, thv2);
        amin2u = pmin_u16x2(amin2u, mb & 0x7fff7fffu);
        unsigned r9_0 = ((mb >> 15) & 1u) ^ 1u;
        unsigned r9_1 = (mb >> 31) ^ 1u;

        unsigned wA0 = r8_0 ? recL0.w : recL0.z;
        unsigned wB0 = r8_0 ? recR0.w : recR0.z;
        unsigned ws0 = r7_0 ? wB0 : wA0;
        unsigned short wb0 = (unsigned short)(r9_0 ? (ws0 >> 16) : (ws0 & 0xffffu));
        unsigned wA1 = r8_1 ? recL1.w : recL1.z;
        unsigned wB1 = r8_1 ? recR1.w : recR1.z;
        unsigned ws1 = r7_1 ? wB1 : wA1;
        unsigned short wb1 = (unsigned short)(r9_1 ? (ws1 >> 16) : (ws1 & 0xffffu));

        float o0 = f16lo_to_f32(amin2u) * __half2float(__ushort_as_half(wb0));
        float o1 = f16hi_to_f32(amin2u) * __half2float(__ushort_as_half(wb1));
        int col0 = g * 32 + wv * 2;
        res[(lane << 7) + ((col0 + lane) & 127)]     = o0;
        res[(lane << 7) + ((col0 + 1 + lane) & 127)] = o1;
    }
    __syncthreads();

    // ---- coalesced output ----
    float* obase = out + (size_t)(tb * 128);
    #pragma unroll
    for (int k = 0; k < 8; ++k) {
        int idx = k * 1024 + tid;
        int rr = idx >> 7, cc = idx & 127;
        float v = res[(rr << 7) + ((cc + rr) & 127)];
        obase[((size_t)panel * 64 + rr) * TT + cc] = v;
    }
}

// ===================== fallback (round-4, proven 541us) =====================
#define F_SP 32
#define F_TG 16
#define F_GROUPS 8
#define F_TPB (F_TG * F_GROUPS)
#define F_NPANELS (BB / F_SP)
#define F_LDS 147456

__global__ __launch_bounds__(512, 1)
void rhf_fallback(const float* __restrict__ x, const float* __restrict__ thr_g,
                  const int* __restrict__ ord_g, const float* __restrict__ wts,
                  float* __restrict__ out) {
    extern __shared__ char smem[];
    float*        xs  = (float*)(smem);
    unsigned int* pk  = (unsigned int*)(smem + 65536);
    float*        res = (float*)(smem + 131072);
    const int tid = threadIdx.x, s = tid & 31, slot = tid >> 5;
    const int panel = blockIdx.x & (F_NPANELS - 1), tb = blockIdx.x >> 7;
    const float* xbase = x + (size_t)panel * F_SP * CC;
    #pragma unroll
    for (int k = 0; k < (F_SP * CC) / 512; ++k) {
        int idx = k * 512 + tid, r = idx >> 9, c = idx & 511;
        xs[(c << 5) + r] = xbase[r * CC + c];
    }
    float4 pthr[8]; int4 pord[8]; float tthr[3]; int tord[3];
    auto prefetch = [&](int g) {
        const size_t base = (size_t)(tb * F_TPB + g * F_TG + slot) * NN;
        #pragma unroll
        for (int k = 0; k < 8; ++k) {
            int j = k * 128 + 4 * s;
            if (j < 1020) { pthr[k] = *(const float4*)(thr_g + base + j);
                            pord[k] = *(const int4*)(ord_g + base + j); }
            else { tthr[0]=thr_g[base+1020]; tord[0]=ord_g[base+1020];
                   tthr[1]=thr_g[base+1021]; tord[1]=ord_g[base+1021];
                   tthr[2]=thr_g[base+1022]; tord[2]=ord_g[base+1022]; }
        }
    };
    auto pack1 = [](float f, int o) -> unsigned int {
        return ((unsigned int)o << 16) | (unsigned int)__half_as_ushort(__float2half(f));
    };
    auto commit = [&]() {
        unsigned int* pt = pk + (slot << 10);
        #pragma unroll
        for (int k = 0; k < 8; ++k) {
            int j = k * 128 + 4 * s;
            if (j < 1020) {
                pt[1+j+0]=pack1(pthr[k].x,pord[k].x); pt[1+j+1]=pack1(pthr[k].y,pord[k].y);
                pt[1+j+2]=pack1(pthr[k].z,pord[k].z); pt[1+j+3]=pack1(pthr[k].w,pord[k].w);
            } else { pt[1+1020]=pack1(tthr[0],tord[0]); pt[1+1021]=pack1(tthr[1],tord[1]);
                     pt[1+1022]=pack1(tthr[2],tord[2]); }
        }
    };
    prefetch(0);
    __builtin_amdgcn_sched_barrier(0);
    for (int g = 0; g < F_GROUPS; ++g) {
        __syncthreads();
        commit();
        __syncthreads();
        if (g + 1 < F_GROUPS) prefetch(g + 1);
        __builtin_amdgcn_sched_barrier(0);
        const int t = tb * F_TPB + g * F_TG + slot;
        const unsigned int* pkt = pk + (slot << 10);
        float minm = __builtin_inff();
        int sl = 1;
        unsigned int cur = pkt[1];
        #pragma unroll
        for (int d = 0; d < DEPTH; ++d) {
            uint2 ch;
            if (d < DEPTH - 1) ch = *(const uint2*)(pkt + 2 * sl);
            float thv = __half2float(__ushort_as_half((unsigned short)(cur & 0xffffu)));
            int orv = (int)(cur >> 16);
            float feat = xs[(orv << 5) + s];
            float m = feat - thv;
            bool take = fabsf(m) < fabsf(minm);
            minm = take ? m : minm;
            int right = (m > 0.0f) ? 1 : 0;
            sl = 2 * sl + right;
            if (d < DEPTH - 1) cur = right ? ch.y : ch.x;
        }
        int leaf = sl - NL;
        float w = wts[(size_t)t * NL + leaf];
        int col = g * F_TG + slot;
        res[(s << 7) + ((col + s) & 127)] = fabsf(minm) * w;
    }
    __syncthreads();
    float* obase = out + (size_t)panel * F_SP * TT + (size_t)tb * F_TPB;
    #pragma unroll
    for (int k = 0; k < (F_SP * F_TPB) / 512; ++k) {
        int idx = k * 512 + tid, rr = idx >> 7, c = idx & 127;
        obase[(size_t)rr * TT + c] = res[(rr << 7) + ((c + rr) & 127)];
    }
}

// ===================== launch =====================
extern "C" void kernel_launch(void* const* d_in, const int* in_sizes, int n_in,
                              void* d_out, int out_size, void* d_ws, size_t ws_size,
                              hipStream_t stream) {
    const float* x    = (const float*)d_in[0];
    const float* thr  = (const float*)d_in[1];
    const int*   ordv = (const int*)d_in[2];
    const float* wts  = (const float*)d_in[3];
    float*       out  = (float*)d_out;

    const size_t pk_bytes   = (size_t)TT * 512 * 4;    // 8 MB
    const size_t tail_bytes = (size_t)TT * 256 * 16;   // 16 MB
    const size_t xt_bytes   = (size_t)CC * BB * 2;     // 4 MB

    if (d_ws && ws_size >= pk_bytes + tail_bytes + xt_bytes) {
        unsigned*       pk_lo = (unsigned*)d_ws;
        uint4*          tails = (uint4*)((char*)d_ws + pk_bytes);
        unsigned short* xt16  = (unsigned short*)((char*)d_ws + pk_bytes + tail_bytes);
        pack_trees<<<TT, 256, 0, stream>>>(thr, ordv, wts, pk_lo, tails);
        dim3 gx(BB / 64, CC / 64);
        pack_x16<<<gx, 256, 0, stream>>>(x, xt16);
        (void)hipFuncSetAttribute((const void*)rhf_main,
                            hipFuncAttributeMaxDynamicSharedMemorySize, LDS_BYTES);
        rhf_main<<<2048, 1024, LDS_BYTES, stream>>>(pk_lo, tails, xt16, out);
    } else {
        (void)hipFuncSetAttribute((const void*)rhf_fallback,
                            hipFuncAttributeMaxDynamicSharedMemorySize, F_LDS);
        rhf_fallback<<<F_NPANELS * (TT / F_TPB), 512, F_LDS, stream>>>(x, thr, ordv, wts, out);
    }
}

// Round 11
// 114.587 us; speedup vs baseline: 1.0394x; 1.0394x over previous
//
#include <hip/hip_runtime.h>
#include <hip/hip_fp16.h>

#define BB 4096
#define CC 512
#define TT 4096
#define NN 1023
#define NL 1024

// ===================== pre-kernels (write d_ws) =====================

__device__ __forceinline__ unsigned pack_node(float th, int o) {
    return ((unsigned)o << 16) | (unsigned)__half_as_ushort(__float2half(th));
}

// pk_lo[t][j] j=0..255: slot j -> node j-1 (depths 0..7); slot 0 = 0.  (1KB/tree)
// p8[t][j]   j=0..127: level-8 candidate pair for depth-7 slot 128+j:
//            {node 255+2j, node 256+2j}                               (8B)
// tails[t][i] i=0..255: level-9 pair + leaf weights for depth-8 slot 256+i:
//            {node 511+2i, node 512+2i, w(4i,4i+1), w(4i+2,4i+3)}     (16B)
__global__ __launch_bounds__(256)
void pack_trees(const float* __restrict__ thr, const int* __restrict__ ord,
                const float* __restrict__ wts, unsigned* __restrict__ pk_lo,
                uint2* __restrict__ p8, uint4* __restrict__ tails) {
    int t = blockIdx.x, tid = threadIdx.x;
    const float* tr = thr + (size_t)t * NN;
    const int*   oo = ord + (size_t)t * NN;
    unsigned* plo = pk_lo + ((size_t)t << 8);
    plo[tid] = (tid == 0) ? 0u : pack_node(tr[tid - 1], oo[tid - 1]);
    if (tid < 128) {
        int j = tid;
        p8[((size_t)t << 7) + j] =
            make_uint2(pack_node(tr[255 + 2 * j], oo[255 + 2 * j]),
                       pack_node(tr[256 + 2 * j], oo[256 + 2 * j]));
    }
    int i = tid;
    int nL = 511 + 2 * i, nR = 512 + 2 * i;
    unsigned ndL = pack_node(tr[nL], oo[nL]);
    unsigned ndR = pack_node(tr[nR], oo[nR]);
    float4 w4 = *(const float4*)(wts + ((size_t)t << 10) + 4 * i);
    unsigned w01 = (unsigned)__half_as_ushort(__float2half(w4.x)) |
                   ((unsigned)__half_as_ushort(__float2half(w4.y)) << 16);
    unsigned w23 = (unsigned)__half_as_ushort(__float2half(w4.z)) |
                   ((unsigned)__half_as_ushort(__float2half(w4.w)) << 16);
    tails[((size_t)t << 8) + i] = make_uint4(ndL, ndR, w01, w23);
}

// xt16[c*4096 + b] = f16bits(x[b][c])
__global__ __launch_bounds__(256)
void pack_x16(const float* __restrict__ x, unsigned short* __restrict__ xt16) {
    __shared__ float tile[64][65];
    int tx = threadIdx.x & 63, ty = threadIdx.x >> 6;   // 64 x 4
    int b0 = blockIdx.x * 64;
    int c0 = blockIdx.y * 64;
    #pragma unroll
    for (int i = 0; i < 16; ++i) {
        int rr = i * 4 + ty;
        tile[rr][tx] = x[(size_t)(b0 + rr) * CC + c0 + tx];
    }
    __syncthreads();
    #pragma unroll
    for (int i = 0; i < 16; ++i) {
        int cr = i * 4 + ty;
        xt16[(size_t)(c0 + cr) * BB + b0 + tx] =
            __half_as_ushort(__float2half(tile[tx][cr]));
    }
}

// ===================== packed helpers =====================
typedef unsigned short u16x2 __attribute__((ext_vector_type(2)));

static __device__ __forceinline__ unsigned psub_f16x2(unsigned a, unsigned b) {
    __half2 ah, bh;
    __builtin_memcpy(&ah, &a, 4);
    __builtin_memcpy(&bh, &b, 4);
    __half2 r = ah - bh;
    unsigned u; __builtin_memcpy(&u, &r, 4); return u;
}
static __device__ __forceinline__ unsigned pmin_u16x2(unsigned a, unsigned b) {
    u16x2 av, bv;
    __builtin_memcpy(&av, &a, 4);
    __builtin_memcpy(&bv, &b, 4);
    u16x2 m = __builtin_elementwise_min(av, bv);
    unsigned u; __builtin_memcpy(&u, &m, 4); return u;
}
static __device__ __forceinline__ float f16lo(unsigned u) {
    return __half2float(__ushort_as_half((unsigned short)(u & 0xffffu)));
}
static __device__ __forceinline__ float f16hi(unsigned u) {
    return __half2float(__ushort_as_half((unsigned short)(u >> 16)));
}

// ===================== main kernel =====================
// grid 2048, XCD-swizzled. 1024 threads = 16 waves (4/SIMD), lane = sample,
// 4 chains/thread, 2 groups x 64 trees (16 waves x 4). Depths 0..7 staged
// (256 slots, 1KB/tree, wave-private). Level 8 via 8B p8 rec, level 9 +
// weights via 16B tail rec (both exact, L2).
// LDS (160 KiB): xs16 u16[512][64] 64K @0 | trees 64K @64K | res f32[64][128] 32K @128K
#define LDS_BYTES 163840

typedef __attribute__((address_space(1))) const void gv_t;
typedef __attribute__((address_space(3))) void lv_t;

__global__ __launch_bounds__(1024, 1)
void rhf_main(const unsigned* __restrict__ pk_lo, const uint2* __restrict__ p8g,
              const uint4* __restrict__ tails, const unsigned short* __restrict__ xt16,
              float* __restrict__ out) {
    extern __shared__ char smem[];
    unsigned short* xs16 = (unsigned short*)smem;
    unsigned*       trl  = (unsigned*)(smem + 65536);
    float*          res  = (float*)(smem + 131072);

    const int tid  = threadIdx.x;
    const int lane = tid & 63;
    const int wv   = tid >> 6;          // 0..15
    const int bi   = blockIdx.x;
    const int tb    = ((bi & 7) << 2) + ((bi >> 3) >> 6);   // 0..31
    const int panel = (bi >> 3) & 63;                       // 0..63

    // ---- per-wave tree DMA: 4 trees x 1KB = 4KB = 4 x (64 lanes x 16B) ----
    const char* gsrc0 = (const char*)pk_lo + ((size_t)(tb * 128) << 10);
    char* ldst = (char*)trl + wv * 4096 + lane * 16;
    auto dma = [&](int g) {
        const char* s = gsrc0 + ((size_t)(g * 64 + wv * 4) << 10) + lane * 16;
        #pragma unroll
        for (int q = 0; q < 4; ++q)
            __builtin_amdgcn_global_load_lds((gv_t*)(s + q * 1024),
                                             (lv_t*)(ldst + q * 1024), 16, 0, 0);
    };

    dma(0);

    // ---- stage xs16 (coalesced 16B, linear LDS writes) ----
    {
        const unsigned short* src = xt16 + (size_t)panel * 64;
        #pragma unroll
        for (int k = 0; k < 4; ++k) {
            int i4 = k * 1024 + tid;
            int c  = i4 >> 3;
            int o8 = (i4 & 7) << 3;
            uint4 v = *(const uint4*)(src + (size_t)c * BB + o8);
            *(uint4*)(xs16 + ((size_t)i4 << 3)) = v;
        }
    }
    __syncthreads();   // xs16 visible; DMA(0) drained

    // packed eval: one level for two chains
    auto evalpair = [&](unsigned nd_a, unsigned nd_b, unsigned& amin,
                        unsigned& r_a, unsigned& r_b) {
        unsigned thv2 = (nd_a & 0xffffu) | (nd_b << 16);
        unsigned short fa = xs16[((nd_a >> 16) << 6) + lane];
        unsigned short fb = xs16[((nd_b >> 16) << 6) + lane];
        unsigned feat2 = (unsigned)fa | ((unsigned)fb << 16);
        unsigned mb = psub_f16x2(feat2, thv2);
        amin = pmin_u16x2(amin, mb & 0x7fff7fffu);
        r_a = ((mb >> 15) & 1u) ^ 1u;
        r_b = (mb >> 31) ^ 1u;
    };

    #pragma unroll 1
    for (int g = 0; g < 2; ++g) {
        if (g > 0) {
            asm volatile("s_waitcnt vmcnt(0)" ::: "memory");   // DMA(1) landed
            __builtin_amdgcn_sched_barrier(0);
        }
        const int t0 = tb * 128 + g * 64 + wv * 4;
        const unsigned* pkw = trl + wv * 1024;

        unsigned amin01 = 0x7c007c00u, amin23 = 0x7c007c00u;
        int sl0 = 1, sl1 = 1, sl2 = 1, sl3 = 1;
        unsigned nd0 = pkw[1], nd1 = pkw[256 + 1], nd2 = pkw[512 + 1], nd3 = pkw[768 + 1];

        // ---- levels 0..6 (staged child-pair reads) ----
        #pragma unroll
        for (int d = 0; d < 7; ++d) {
            uint2 ch0 = *(const uint2*)(pkw +       2 * sl0);
            uint2 ch1 = *(const uint2*)(pkw + 256 + 2 * sl1);
            uint2 ch2 = *(const uint2*)(pkw + 512 + 2 * sl2);
            uint2 ch3 = *(const uint2*)(pkw + 768 + 2 * sl3);
            unsigned r0, r1, r2, r3;
            evalpair(nd0, nd1, amin01, r0, r1);
            evalpair(nd2, nd3, amin23, r2, r3);
            sl0 = 2 * sl0 + (int)r0; nd0 = r0 ? ch0.y : ch0.x;
            sl1 = 2 * sl1 + (int)r1; nd1 = r1 ? ch1.y : ch1.x;
            sl2 = 2 * sl2 + (int)r2; nd2 = r2 ? ch2.y : ch2.x;
            sl3 = 2 * sl3 + (int)r3; nd3 = r3 ? ch3.y : ch3.x;
        }

        // ---- level 7: p8 recs (exact, 8B each) then eval ----
        const uint2* p8t = p8g + ((size_t)t0 << 7);
        uint2 q0 = p8t[        sl0 - 128];
        uint2 q1 = p8t[128 +   sl1 - 128];
        uint2 q2 = p8t[256 +   sl2 - 128];
        uint2 q3 = p8t[384 +   sl3 - 128];
        {
            unsigned r0, r1, r2, r3;
            evalpair(nd0, nd1, amin01, r0, r1);
            evalpair(nd2, nd3, amin23, r2, r3);
            sl0 = 2 * sl0 + (int)r0; nd0 = r0 ? q0.y : q0.x;
            sl1 = 2 * sl1 + (int)r1; nd1 = r1 ? q1.y : q1.x;
            sl2 = 2 * sl2 + (int)r2; nd2 = r2 ? q2.y : q2.x;
            sl3 = 2 * sl3 + (int)r3; nd3 = r3 ? q3.y : q3.x;
        }

        // ---- level 8: tail recs (exact, 16B each); next-group DMA after ----
        const uint4* tt = tails + ((size_t)t0 << 8);
        uint4 e0 = tt[        sl0 - 256];
        uint4 e1 = tt[256 +   sl1 - 256];
        uint4 e2 = tt[512 +   sl2 - 256];
        uint4 e3 = tt[768 +   sl3 - 256];
        if (g == 0) { dma(1); __builtin_amdgcn_sched_barrier(0); }
        unsigned w0, w1, w2, w3;
        {
            unsigned r0, r1, r2, r3;
            evalpair(nd0, nd1, amin01, r0, r1);
            evalpair(nd2, nd3, amin23, r2, r3);
            nd0 = r0 ? e0.y : e0.x;  w0 = r0 ? e0.w : e0.z;
            nd1 = r1 ? e1.y : e1.x;  w1 = r1 ? e1.w : e1.z;
            nd2 = r2 ? e2.y : e2.x;  w2 = r2 ? e2.w : e2.z;
            nd3 = r3 ? e3.y : e3.x;  w3 = r3 ? e3.w : e3.z;
        }

        // ---- level 9 + weight ----
        {
            unsigned r0, r1, r2, r3;
            evalpair(nd0, nd1, amin01, r0, r1);
            evalpair(nd2, nd3, amin23, r2, r3);
            unsigned short wb0 = (unsigned short)(r0 ? (w0 >> 16) : (w0 & 0xffffu));
            unsigned short wb1 = (unsigned short)(r1 ? (w1 >> 16) : (w1 & 0xffffu));
            unsigned short wb2 = (unsigned short)(r2 ? (w2 >> 16) : (w2 & 0xffffu));
            unsigned short wb3 = (unsigned short)(r3 ? (w3 >> 16) : (w3 & 0xffffu));
            float o0 = f16lo(amin01) * __half2float(__ushort_as_half(wb0));
            float o1 = f16hi(amin01) * __half2float(__ushort_as_half(wb1));
            float o2 = f16lo(amin23) * __half2float(__ushort_as_half(wb2));
            float o3 = f16hi(amin23) * __half2float(__ushort_as_half(wb3));
            int col0 = g * 64 + wv * 4;
            res[(lane << 7) + ((col0 +     lane) & 127)] = o0;
            res[(lane << 7) + ((col0 + 1 + lane) & 127)] = o1;
            res[(lane << 7) + ((col0 + 2 + lane) & 127)] = o2;
            res[(lane << 7) + ((col0 + 3 + lane) & 127)] = o3;
        }
    }
    __syncthreads();

    // ---- coalesced output ----
    float* obase = out + (size_t)(tb * 128);
    #pragma unroll
    for (int k = 0; k < 8; ++k) {
        int idx = k * 1024 + tid;
        int rr = idx >> 7, cc = idx & 127;
        float v = res[(rr << 7) + ((cc + rr) & 127)];
        obase[((size_t)panel * 64 + rr) * TT + cc] = v;
    }
}

// ===================== fallback (round-4, proven 541us) =====================
#define F_SP 32
#define F_TG 16
#define F_GROUPS 8
#define F_TPB (F_TG * F_GROUPS)
#define F_NPANELS (BB / F_SP)
#define F_LDS 147456

__global__ __launch_bounds__(512, 1)
void rhf_fallback(const float* __restrict__ x, const float* __restrict__ thr_g,
                  const int* __restrict__ ord_g, const float* __restrict__ wts,
                  float* __restrict__ out) {
    extern __shared__ char smem[];
    float*        xs  = (float*)(smem);
    unsigned int* pk  = (unsigned int*)(smem + 65536);
    float*        res = (float*)(smem + 131072);
    const int tid = threadIdx.x, s = tid & 31, slot = tid >> 5;
    const int panel = blockIdx.x & (F_NPANELS - 1), tb = blockIdx.x >> 7;
    const float* xbase = x + (size_t)panel * F_SP * CC;
    #pragma unroll
    for (int k = 0; k < (F_SP * CC) / 512; ++k) {
        int idx = k * 512 + tid, r = idx >> 9, c = idx & 511;
        xs[(c << 5) + r] = xbase[r * CC + c];
    }
    float4 pthr[8]; int4 pord[8]; float tthr[3]; int tord[3];
    auto prefetch = [&](int g) {
        const size_t base = (size_t)(tb * F_TPB + g * F_TG + slot) * NN;
        #pragma unroll
        for (int k = 0; k < 8; ++k) {
            int j = k * 128 + 4 * s;
            if (j < 1020) { pthr[k] = *(const float4*)(thr_g + base + j);
                            pord[k] = *(const int4*)(ord_g + base + j); }
            else { tthr[0]=thr_g[base+1020]; tord[0]=ord_g[base+1020];
                   tthr[1]=thr_g[base+1021]; tord[1]=ord_g[base+1021];
                   tthr[2]=thr_g[base+1022]; tord[2]=ord_g[base+1022]; }
        }
    };
    auto pack1 = [](float f, int o) -> unsigned int {
        return ((unsigned int)o << 16) | (unsigned int)__half_as_ushort(__float2half(f));
    };
    auto commit = [&]() {
        unsigned int* pt = pk + (slot << 10);
        #pragma unroll
        for (int k = 0; k < 8; ++k) {
            int j = k * 128 + 4 * s;
            if (j < 1020) {
                pt[1+j+0]=pack1(pthr[k].x,pord[k].x); pt[1+j+1]=pack1(pthr[k].y,pord[k].y);
                pt[1+j+2]=pack1(pthr[k].z,pord[k].z); pt[1+j+3]=pack1(pthr[k].w,pord[k].w);
            } else { pt[1+1020]=pack1(tthr[0],tord[0]); pt[1+1021]=pack1(tthr[1],tord[1]);
                     pt[1+1022]=pack1(tthr[2],tord[2]); }
        }
    };
    prefetch(0);
    __builtin_amdgcn_sched_barrier(0);
    for (int g = 0; g < F_GROUPS; ++g) {
        __syncthreads();
        commit();
        __syncthreads();
        if (g + 1 < F_GROUPS) prefetch(g + 1);
        __builtin_amdgcn_sched_barrier(0);
        const int t = tb * F_TPB + g * F_TG + slot;
        const unsigned int* pkt = pk + (slot << 10);
        float minm = __builtin_inff();
        int sl = 1;
        unsigned int cur = pkt[1];
        #pragma unroll
        for (int d = 0; d < 10; ++d) {
            uint2 ch;
            if (d < 9) ch = *(const uint2*)(pkt + 2 * sl);
            float thv = __half2float(__ushort_as_half((unsigned short)(cur & 0xffffu)));
            int orv = (int)(cur >> 16);
            float feat = xs[(orv << 5) + s];
            float m = feat - thv;
            bool take = fabsf(m) < fabsf(minm);
            minm = take ? m : minm;
            int right = (m > 0.0f) ? 1 : 0;
            sl = 2 * sl + right;
            if (d < 9) cur = right ? ch.y : ch.x;
        }
        int leaf = sl - NL;
        float w = wts[(size_t)t * NL + leaf];
        int col = g * F_TG + slot;
        res[(s << 7) + ((col + s) & 127)] = fabsf(minm) * w;
    }
    __syncthreads();
    float* obase = out + (size_t)panel * F_SP * TT + (size_t)tb * F_TPB;
    #pragma unroll
    for (int k = 0; k < (F_SP * F_TPB) / 512; ++k) {
        int idx = k * 512 + tid, rr = idx >> 7, c = idx & 127;
        obase[(size_t)rr * TT + c] = res[(rr << 7) + ((c + rr) & 127)];
    }
}

// ===================== launch =====================
extern "C" void kernel_launch(void* const* d_in, const int* in_sizes, int n_in,
                              void* d_out, int out_size, void* d_ws, size_t ws_size,
                              hipStream_t stream) {
    const float* x    = (const float*)d_in[0];
    const float* thr  = (const float*)d_in[1];
    const int*   ordv = (const int*)d_in[2];
    const float* wts  = (const float*)d_in[3];
    float*       out  = (float*)d_out;

    const size_t pk_bytes   = (size_t)TT * 256 * 4;    // 4 MB
    const size_t p8_bytes   = (size_t)TT * 128 * 8;    // 4 MB
    const size_t tail_bytes = (size_t)TT * 256 * 16;   // 16 MB
    const size_t xt_bytes   = (size_t)CC * BB * 2;     // 4 MB

    if (d_ws && ws_size >= pk_bytes + p8_bytes + tail_bytes + xt_bytes) {
        unsigned*       pk_lo = (unsigned*)d_ws;
        uint2*          p8    = (uint2*)((char*)d_ws + pk_bytes);
        uint4*          tails = (uint4*)((char*)d_ws + pk_bytes + p8_bytes);
        unsigned short* xt16  = (unsigned short*)((char*)d_ws + pk_bytes + p8_bytes + tail_bytes);
        pack_trees<<<TT, 256, 0, stream>>>(thr, ordv, wts, pk_lo, p8, tails);
        dim3 gx(BB / 64, CC / 64);
        pack_x16<<<gx, 256, 0, stream>>>(x, xt16);
        (void)hipFuncSetAttribute((const void*)rhf_main,
                            hipFuncAttributeMaxDynamicSharedMemorySize, LDS_BYTES);
        rhf_main<<<2048, 1024, LDS_BYTES, stream>>>(pk_lo, p8, tails, xt16, out);
    } else {
        (void)hipFuncSetAttribute((const void*)rhf_fallback,
                            hipFuncAttributeMaxDynamicSharedMemorySize, F_LDS);
        rhf_fallback<<<F_NPANELS * (TT / F_TPB), 512, F_LDS, stream>>>(x, thr, ordv, wts, out);
    }
}

// Round 13
// 111.785 us; speedup vs baseline: 1.0654x; 1.0251x over previous
//
#include <hip/hip_runtime.h>
#include <hip/hip_fp16.h>

#define BB 4096
#define CC 512
#define TT 4096
#define NN 1023
#define NL 1024

// ===================== pre-kernels (write d_ws) =====================

// node record: (ord*128) in high 16 bits (byte offset into a 64-sample xs row),
// f16(thr) in low 16. ord<512 -> ord*128 <= 65408 fits u16.
__device__ __forceinline__ unsigned pack_node(float th, int o) {
    return ((unsigned)o << 23) | (unsigned)__half_as_ushort(__float2half(th));
}

// pk_lo[t][j] j=0..127: slot j -> node j-1 (depths 0..6); slot 0 = 0.  (512B/tree)
// g7[t][j]  j=0..63 : depth-7 pair for depth-6 slot 64+j  : {tr[127+2j], tr[128+2j]}
// g8[t][j]  j=0..127: depth-8 pair for depth-7 slot 128+j : {tr[255+2j], tr[256+2j]}
// tails[t][i] i=0..255: depth-9 pair + leaf weights for depth-8 slot 256+i:
//            {tr[511+2i], tr[512+2i], w(4i,4i+1), w(4i+2,4i+3)}
__global__ __launch_bounds__(256)
void pack_trees(const float* __restrict__ thr, const int* __restrict__ ord,
                const float* __restrict__ wts, unsigned* __restrict__ pk_lo,
                uint2* __restrict__ g7, uint2* __restrict__ g8,
                uint4* __restrict__ tails) {
    int t = blockIdx.x, tid = threadIdx.x;
    const float* tr = thr + (size_t)t * NN;
    const int*   oo = ord + (size_t)t * NN;
    if (tid < 128) {
        unsigned* plo = pk_lo + ((size_t)t << 7);
        plo[tid] = (tid == 0) ? 0u : pack_node(tr[tid - 1], oo[tid - 1]);
    }
    if (tid < 64) {
        int j = tid;
        g7[((size_t)t << 6) + j] =
            make_uint2(pack_node(tr[127 + 2 * j], oo[127 + 2 * j]),
                       pack_node(tr[128 + 2 * j], oo[128 + 2 * j]));
    }
    if (tid < 128) {
        int j = tid;
        g8[((size_t)t << 7) + j] =
            make_uint2(pack_node(tr[255 + 2 * j], oo[255 + 2 * j]),
                       pack_node(tr[256 + 2 * j], oo[256 + 2 * j]));
    }
    int i = tid;
    int nL = 511 + 2 * i, nR = 512 + 2 * i;
    unsigned ndL = pack_node(tr[nL], oo[nL]);
    unsigned ndR = pack_node(tr[nR], oo[nR]);
    float4 w4 = *(const float4*)(wts + ((size_t)t << 10) + 4 * i);
    unsigned w01 = (unsigned)__half_as_ushort(__float2half(w4.x)) |
                   ((unsigned)__half_as_ushort(__float2half(w4.y)) << 16);
    unsigned w23 = (unsigned)__half_as_ushort(__float2half(w4.z)) |
                   ((unsigned)__half_as_ushort(__float2half(w4.w)) << 16);
    tails[((size_t)t << 8) + i] = make_uint4(ndL, ndR, w01, w23);
}

// xt16[c*4096 + b] = f16bits(x[b][c])
__global__ __launch_bounds__(256)
void pack_x16(const float* __restrict__ x, unsigned short* __restrict__ xt16) {
    __shared__ float tile[64][65];
    int tx = threadIdx.x & 63, ty = threadIdx.x >> 6;   // 64 x 4
    int b0 = blockIdx.x * 64;
    int c0 = blockIdx.y * 64;
    #pragma unroll
    for (int i = 0; i < 16; ++i) {
        int rr = i * 4 + ty;
        tile[rr][tx] = x[(size_t)(b0 + rr) * CC + c0 + tx];
    }
    __syncthreads();
    #pragma unroll
    for (int i = 0; i < 16; ++i) {
        int cr = i * 4 + ty;
        xt16[(size_t)(c0 + cr) * BB + b0 + tx] =
            __half_as_ushort(__float2half(tile[tx][cr]));
    }
}

// ===================== packed helpers =====================
typedef unsigned short u16x2 __attribute__((ext_vector_type(2)));

static __device__ __forceinline__ unsigned psub_f16x2(unsigned a, unsigned b) {
    __half2 ah, bh;
    __builtin_memcpy(&ah, &a, 4);
    __builtin_memcpy(&bh, &b, 4);
    __half2 r = ah - bh;
    unsigned u; __builtin_memcpy(&u, &r, 4); return u;
}
static __device__ __forceinline__ unsigned pmin_u16x2(unsigned a, unsigned b) {
    u16x2 av, bv;
    __builtin_memcpy(&av, &a, 4);
    __builtin_memcpy(&bv, &b, 4);
    u16x2 m = __builtin_elementwise_min(av, bv);
    unsigned u; __builtin_memcpy(&u, &m, 4); return u;
}
static __device__ __forceinline__ float f16lo(unsigned u) {
    return __half2float(__ushort_as_half((unsigned short)(u & 0xffffu)));
}
static __device__ __forceinline__ float f16hi(unsigned u) {
    return __half2float(__ushort_as_half((unsigned short)(u >> 16)));
}

// ===================== main kernel =====================
// grid 2048, XCD-swizzled. 1024 threads = 16 waves (4/SIMD), lane = sample,
// 8 chains/thread, SINGLE group of 128 trees (16 waves x 8). Depths 0..6 staged
// (128 slots, 512B/tree, wave-private). Levels 6,7 via 8B g7/g8 recs, level 8/9
// + weights via 16B tails (all exact, XCD-L2-resident, SGPR bases).
// LDS (exactly 160 KiB): xs16 64K @0 | trees 64K @64K | res f32[64][128] 32K @128K
#define LDS_BYTES 163840

typedef __attribute__((address_space(1))) const void gv_t;
typedef __attribute__((address_space(3))) void lv_t;

__global__ __launch_bounds__(1024, 1)
void rhf_main(const unsigned* __restrict__ pk_lo, const uint2* __restrict__ g7g,
              const uint2* __restrict__ g8g, const uint4* __restrict__ tails,
              const unsigned short* __restrict__ xt16, float* __restrict__ out) {
    extern __shared__ char smem[];
    const char*     xsb = (const char*)smem;            // xs16 byte base
    unsigned*       trl = (unsigned*)(smem + 65536);
    float*          res = (float*)(smem + 131072);

    const int tid  = threadIdx.x;
    const int lane = tid & 63;
    const int wv   = tid >> 6;          // 0..15
    const int bi   = blockIdx.x;
    const int tb    = ((bi & 7) << 2) + ((bi >> 3) >> 6);   // 0..31
    const int panel = (bi >> 3) & 63;                       // 0..63
    const int lane2 = lane << 1;        // byte offset of this sample in an xs row

    // ---- per-wave tree DMA: 8 trees x 512B = 4KB = 4 x (64 lanes x 16B) ----
    {
        const char* s = (const char*)pk_lo + ((size_t)(tb * 128 + wv * 8) << 9) + lane * 16;
        char* d = (char*)trl + wv * 4096 + lane * 16;
        #pragma unroll
        for (int q = 0; q < 4; ++q)
            __builtin_amdgcn_global_load_lds((gv_t*)(s + q * 1024),
                                             (lv_t*)(d + q * 1024), 16, 0, 0);
    }

    // ---- stage xs16 (coalesced 16B, linear LDS writes) ----
    {
        const unsigned short* src = xt16 + (size_t)panel * 64;
        #pragma unroll
        for (int k = 0; k < 4; ++k) {
            int i4 = k * 1024 + tid;
            int c  = i4 >> 3;
            int o8 = (i4 & 7) << 3;
            uint4 v = *(const uint4*)(src + (size_t)c * BB + o8);
            *(uint4*)((char*)smem + ((size_t)i4 << 4)) = v;
        }
    }
    __syncthreads();   // xs16 visible; tree DMA drained (barrier drains vmcnt)

    const int t0 = tb * 128 + wv * 8;           // wave-uniform first tree
    const unsigned* pkw = trl + wv * 1024;      // this wave's 8 x 128 slots

    // packed eval for chains (a,b): updates amin, returns branch bits
    auto evalpair = [&](unsigned nd_a, unsigned nd_b, unsigned& amin,
                        unsigned& r_a, unsigned& r_b) {
        unsigned thv2 = (nd_a & 0xffffu) | (nd_b << 16);
        unsigned short fa = *(const unsigned short*)(xsb + (nd_a >> 16) + lane2);
        unsigned short fb = *(const unsigned short*)(xsb + (nd_b >> 16) + lane2);
        unsigned feat2 = (unsigned)fa | ((unsigned)fb << 16);
        unsigned mb = psub_f16x2(feat2, thv2);
        amin = pmin_u16x2(amin, mb & 0x7fff7fffu);
        r_a = ((mb >> 15) & 1u) ^ 1u;
        r_b = (mb >> 31) ^ 1u;
    };

    unsigned amin[4];
    int      sl[8];
    unsigned nd[8];
    unsigned r[8];
    #pragma unroll
    for (int p = 0; p < 4; ++p) amin[p] = 0x7c007c00u;
    #pragma unroll
    for (int c = 0; c < 8; ++c) { sl[c] = 1; nd[c] = pkw[c * 128 + 1]; }

    // ---- levels 0..5 (children from LDS) ----
    #pragma unroll
    for (int d = 0; d < 6; ++d) {
        uint2 ch[8];
        #pragma unroll
        for (int c = 0; c < 8; ++c)
            ch[c] = *(const uint2*)(pkw + c * 128 + 2 * sl[c]);
        #pragma unroll
        for (int p = 0; p < 4; ++p)
            evalpair(nd[2 * p], nd[2 * p + 1], amin[p], r[2 * p], r[2 * p + 1]);
        #pragma unroll
        for (int c = 0; c < 8; ++c) {
            sl[c] = 2 * sl[c] + (int)r[c];
            nd[c] = r[c] ? ch[c].y : ch[c].x;
        }
    }

    // ---- level 6: depth-7 pairs from g7 (8B, L2) ----
    {
        uint2 q[8];
        #pragma unroll
        for (int c = 0; c < 8; ++c)
            q[c] = g7g[((size_t)(t0 + c) << 6) + (sl[c] - 64)];
        #pragma unroll
        for (int p = 0; p < 4; ++p)
            evalpair(nd[2 * p], nd[2 * p + 1], amin[p], r[2 * p], r[2 * p + 1]);
        #pragma unroll
        for (int c = 0; c < 8; ++c) {
            sl[c] = 2 * sl[c] + (int)r[c];
            nd[c] = r[c] ? q[c].y : q[c].x;
        }
    }

    // ---- level 7: depth-8 pairs from g8 (8B, L2) ----
    {
        uint2 q[8];
        #pragma unroll
        for (int c = 0; c < 8; ++c)
            q[c] = g8g[((size_t)(t0 + c) << 7) + (sl[c] - 128)];
        #pragma unroll
        for (int p = 0; p < 4; ++p)
            evalpair(nd[2 * p], nd[2 * p + 1], amin[p], r[2 * p], r[2 * p + 1]);
        #pragma unroll
        for (int c = 0; c < 8; ++c) {
            sl[c] = 2 * sl[c] + (int)r[c];
            nd[c] = r[c] ? q[c].y : q[c].x;
        }
    }

    // ---- level 8: tails (16B, L2) -> depth-9 node + weight word ----
    unsigned wsel[8];
    {
        uint4 e[8];
        #pragma unroll
        for (int c = 0; c < 8; ++c)
            e[c] = tails[((size_t)(t0 + c) << 8) + (sl[c] - 256)];
        #pragma unroll
        for (int p = 0; p < 4; ++p)
            evalpair(nd[2 * p], nd[2 * p + 1], amin[p], r[2 * p], r[2 * p + 1]);
        #pragma unroll
        for (int c = 0; c < 8; ++c) {
            nd[c]   = r[c] ? e[c].y : e[c].x;
            wsel[c] = r[c] ? e[c].w : e[c].z;
        }
    }

    // ---- level 9 + weight, write res ----
    {
        #pragma unroll
        for (int p = 0; p < 4; ++p)
            evalpair(nd[2 * p], nd[2 * p + 1], amin[p], r[2 * p], r[2 * p + 1]);
        #pragma unroll
        for (int c = 0; c < 8; ++c) {
            unsigned short wb = (unsigned short)(r[c] ? (wsel[c] >> 16) : (wsel[c] & 0xffffu));
            float am = (c & 1) ? f16hi(amin[c >> 1]) : f16lo(amin[c >> 1]);
            float o  = am * __half2float(__ushort_as_half(wb));
            int col = wv * 8 + c;
            res[(lane << 7) + ((col + lane) & 127)] = o;
        }
    }
    __syncthreads();

    // ---- coalesced output ----
    float* obase = out + (size_t)(tb * 128);
    #pragma unroll
    for (int k = 0; k < 8; ++k) {
        int idx = k * 1024 + tid;
        int rr = idx >> 7, cc = idx & 127;
        float v = res[(rr << 7) + ((cc + rr) & 127)];
        obase[((size_t)panel * 64 + rr) * TT + cc] = v;
    }
}

// ===================== fallback (round-4, proven 541us) =====================
#define F_SP 32
#define F_TG 16
#define F_GROUPS 8
#define F_TPB (F_TG * F_GROUPS)
#define F_NPANELS (BB / F_SP)
#define F_LDS 147456

__global__ __launch_bounds__(512, 1)
void rhf_fallback(const float* __restrict__ x, const float* __restrict__ thr_g,
                  const int* __restrict__ ord_g, const float* __restrict__ wts,
                  float* __restrict__ out) {
    extern __shared__ char smem[];
    float*        xs  = (float*)(smem);
    unsigned int* pk  = (unsigned int*)(smem + 65536);
    float*        res = (float*)(smem + 131072);
    const int tid = threadIdx.x, s = tid & 31, slot = tid >> 5;
    const int panel = blockIdx.x & (F_NPANELS - 1), tb = blockIdx.x >> 7;
    const float* xbase = x + (size_t)panel * F_SP * CC;
    #pragma unroll
    for (int k = 0; k < (F_SP * CC) / 512; ++k) {
        int idx = k * 512 + tid, r = idx >> 9, c = idx & 511;
        xs[(c << 5) + r] = xbase[r * CC + c];
    }
    float4 pthr[8]; int4 pord[8]; float tthr[3]; int tord[3];
    auto prefetch = [&](int g) {
        const size_t base = (size_t)(tb * F_TPB + g * F_TG + slot) * NN;
        #pragma unroll
        for (int k = 0; k < 8; ++k) {
            int j = k * 128 + 4 * s;
            if (j < 1020) { pthr[k] = *(const float4*)(thr_g + base + j);
                            pord[k] = *(const int4*)(ord_g + base + j); }
            else { tthr[0]=thr_g[base+1020]; tord[0]=ord_g[base+1020];
                   tthr[1]=thr_g[base+1021]; tord[1]=ord_g[base+1021];
                   tthr[2]=thr_g[base+1022]; tord[2]=ord_g[base+1022]; }
        }
    };
    auto pack1 = [](float f, int o) -> unsigned int {
        return ((unsigned int)o << 16) | (unsigned int)__half_as_ushort(__float2half(f));
    };
    auto commit = [&]() {
        unsigned int* pt = pk + (slot << 10);
        #pragma unroll
        for (int k = 0; k < 8; ++k) {
            int j = k * 128 + 4 * s;
            if (j < 1020) {
                pt[1+j+0]=pack1(pthr[k].x,pord[k].x); pt[1+j+1]=pack1(pthr[k].y,pord[k].y);
                pt[1+j+2]=pack1(pthr[k].z,pord[k].z); pt[1+j+3]=pack1(pthr[k].w,pord[k].w);
            } else { pt[1+1020]=pack1(tthr[0],tord[0]); pt[1+1021]=pack1(tthr[1],tord[1]);
                     pt[1+1022]=pack1(tthr[2],tord[2]); }
        }
    };
    prefetch(0);
    __builtin_amdgcn_sched_barrier(0);
    for (int g = 0; g < F_GROUPS; ++g) {
        __syncthreads();
        commit();
        __syncthreads();
        if (g + 1 < F_GROUPS) prefetch(g + 1);
        __builtin_amdgcn_sched_barrier(0);
        const int t = tb * F_TPB + g * F_TG + slot;
        const unsigned int* pkt = pk + (slot << 10);
        float minm = __builtin_inff();
        int sl = 1;
        unsigned int cur = pkt[1];
        #pragma unroll
        for (int d = 0; d < 10; ++d) {
            uint2 ch;
            if (d < 9) ch = *(const uint2*)(pkt + 2 * sl);
            float thv = __half2float(__ushort_as_half((unsigned short)(cur & 0xffffu)));
            int orv = (int)(cur >> 16);
            float feat = xs[(orv << 5) + s];
            float m = feat - thv;
            bool take = fabsf(m) < fabsf(minm);
            minm = take ? m : minm;
            int right = (m > 0.0f) ? 1 : 0;
            sl = 2 * sl + right;
            if (d < 9) cur = right ? ch.y : ch.x;
        }
        int leaf = sl - NL;
        float w = wts[(size_t)t * NL + leaf];
        int col = g * F_TG + slot;
        res[(s << 7) + ((col + s) & 127)] = fabsf(minm) * w;
    }
    __syncthreads();
    float* obase = out + (size_t)panel * F_SP * TT + (size_t)tb * F_TPB;
    #pragma unroll
    for (int k = 0; k < (F_SP * F_TPB) / 512; ++k) {
        int idx = k * 512 + tid, rr = idx >> 7, c = idx & 127;
        obase[(size_t)rr * TT + c] = res[(rr << 7) + ((c + rr) & 127)];
    }
}

// ===================== launch =====================
extern "C" void kernel_launch(void* const* d_in, const int* in_sizes, int n_in,
                              void* d_out, int out_size, void* d_ws, size_t ws_size,
                              hipStream_t stream) {
    const float* x    = (const float*)d_in[0];
    const float* thr  = (const float*)d_in[1];
    const int*   ordv = (const int*)d_in[2];
    const float* wts  = (const float*)d_in[3];
    float*       out  = (float*)d_out;

    const size_t pk_bytes   = (size_t)TT * 128 * 4;    // 2 MB
    const size_t g7_bytes   = (size_t)TT * 64 * 8;     // 2 MB
    const size_t g8_bytes   = (size_t)TT * 128 * 8;    // 4 MB
    const size_t tail_bytes = (size_t)TT * 256 * 16;   // 16 MB
    const size_t xt_bytes   = (size_t)CC * BB * 2;     // 4 MB

    if (d_ws && ws_size >= pk_bytes + g7_bytes + g8_bytes + tail_bytes + xt_bytes) {
        char* p = (char*)d_ws;
        unsigned*       pk_lo = (unsigned*)p;            p += pk_bytes;
        uint2*          g7    = (uint2*)p;               p += g7_bytes;
        uint2*          g8    = (uint2*)p;               p += g8_bytes;
        uint4*          tails = (uint4*)p;               p += tail_bytes;
        unsigned short* xt16  = (unsigned short*)p;
        pack_trees<<<TT, 256, 0, stream>>>(thr, ordv, wts, pk_lo, g7, g8, tails);
        dim3 gx(BB / 64, CC / 64);
        pack_x16<<<gx, 256, 0, stream>>>(x, xt16);
        (void)hipFuncSetAttribute((const void*)rhf_main,
                            hipFuncAttributeMaxDynamicSharedMemorySize, LDS_BYTES);
        rhf_main<<<2048, 1024, LDS_BYTES, stream>>>(pk_lo, g7, g8, tails, xt16, out);
    } else {
        (void)hipFuncSetAttribute((const void*)rhf_fallback,
                            hipFuncAttributeMaxDynamicSharedMemorySize, F_LDS);
        rhf_fallback<<<F_NPANELS * (TT / F_TPB), 512, F_LDS, stream>>>(x, thr, ordv, wts, out);
    }
}